// Round 7
// baseline (197.676 us; speedup 1.0000x reference)
//
#include <hip/hip_runtime.h>

#define C_DIM 256
#define CK_DIM 32
#define NPIX 4096
#define BATCH 4

typedef __attribute__((ext_vector_type(8))) short bf16x8;     // 8 bf16 = 4 VGPRs
typedef __attribute__((ext_vector_type(4))) float f32x4;
typedef __attribute__((ext_vector_type(16))) float f32x16;
typedef __attribute__((ext_vector_type(4))) unsigned short us4;

__device__ __forceinline__ unsigned short f2bf(float f) {
    union { float f; unsigned int u; } c; c.f = f;
    unsigned int r = c.u + 0x7FFFu + ((c.u >> 16) & 1u);
    return (unsigned short)(r >> 16);
}

// ---------------------------------------------------------------------------
// Kernel 0: pack W (key 0..31, query 32..63, value 64..319) into bf16 [320][256]
// ---------------------------------------------------------------------------
__global__ __launch_bounds__(256) void wprep_kernel(
    const float* __restrict__ kW, const float* __restrict__ qW,
    const float* __restrict__ vW, unsigned short* __restrict__ wbf)
{
    int i4 = (blockIdx.x * 256 + threadIdx.x) * 4;
    int o = i4 >> 8, c = i4 & 255;
    const float* src = (o < 32) ? kW + o * 256 + c
                     : (o < 64) ? qW + (o - 32) * 256 + c
                                : vW + (o - 64) * 256 + c;
    float4 f = *(const float4*)src;
    us4 p; p.x = f2bf(f.x); p.y = f2bf(f.y); p.z = f2bf(f.z); p.w = f2bf(f.w);
    *(us4*)&wbf[i4] = p;
}

// ---------------------------------------------------------------------------
// Kernel A: MFMA projections. Block = (32-pixel tile, b): 512 blocks = 2/CU.
// K-loop now SOFTWARE-PIPELINES the W A-frag global loads (awc/awn double
// registers): if R5/R6's proj wall was W-load L2 latency, this removes it.
// ---------------------------------------------------------------------------
#define XP 264            // xT pitch in shorts (528 B: 16B-aligned, rotates banks)
__global__ __launch_bounds__(256) void proj_kernel(
    const float* __restrict__ x,
    const unsigned short* __restrict__ wbf,
    const float* __restrict__ key_b, const float* __restrict__ query_b,
    const float* __restrict__ value_b,
    unsigned short* __restrict__ kT,
    unsigned short* __restrict__ qT,
    unsigned short* __restrict__ vt)
{
    const int b  = blockIdx.y;
    const int n0 = blockIdx.x * 32;
    const int t  = threadIdx.x;
    const int w    = t >> 6;
    const int lane = t & 63;
    const int mrow = lane & 15;
    const int quad = lane >> 4;
    const int oh   = w >> 1;          // o-half: rows [160*oh, 160*oh+160)
    const int ns   = (w & 1) * 16;    // pixel strip

    __shared__ __align__(16) unsigned short smem[14592];
    #define XT(n, c)       smem[(n) * XP + (c)]
    #define VS(nsb, c, nn) smem[(nsb) * 6144 + (c) * 24 + (nn)]
    #define KQS(n, o)      smem[12288 + (n) * 72 + (o)]

    // ---- stage x^T (bf16) via 4x4 register transpose; coalesced reads
    const float* xb = x + (size_t)b * C_DIM * NPIX + n0;
    const int cb = (t >> 3) * 4;
    const int n4 = (t & 7) * 4;
    #pragma unroll
    for (int it = 0; it < 2; ++it) {
        int c0 = it * 128 + cb;
        float4 r0 = *(const float4*)(xb + (size_t)(c0 + 0) * NPIX + n4);
        float4 r1 = *(const float4*)(xb + (size_t)(c0 + 1) * NPIX + n4);
        float4 r2 = *(const float4*)(xb + (size_t)(c0 + 2) * NPIX + n4);
        float4 r3 = *(const float4*)(xb + (size_t)(c0 + 3) * NPIX + n4);
        float d0[4] = {r0.x, r0.y, r0.z, r0.w};
        float d1[4] = {r1.x, r1.y, r1.z, r1.w};
        float d2[4] = {r2.x, r2.y, r2.z, r2.w};
        float d3[4] = {r3.x, r3.y, r3.z, r3.w};
        #pragma unroll
        for (int d = 0; d < 4; ++d) {
            us4 p; p.x = f2bf(d0[d]); p.y = f2bf(d1[d]);
                   p.z = f2bf(d2[d]); p.w = f2bf(d3[d]);
            *(us4*)&XT(n4 + d, c0) = p;
        }
    }
    __syncthreads();

    // ---- K-loop: 8 steps x 10 MFMA per wave, W-frags double-buffered
    f32x4 acc[10];
    #pragma unroll
    for (int ot = 0; ot < 10; ++ot) acc[ot] = (f32x4){0.f, 0.f, 0.f, 0.f};
    const int obase = oh * 160;
    const unsigned short* wp = wbf + (size_t)(obase + mrow) * 256 + quad * 8;

    bf16x8 awc[10], awn[10];
    #pragma unroll
    for (int ot = 0; ot < 10; ++ot)
        awc[ot] = *(const bf16x8*)(wp + (size_t)ot * 16 * 256);

    #pragma unroll
    for (int ck = 0; ck < 256; ck += 32) {
        bf16x8 bx = *(const bf16x8*)&XT(ns + mrow, ck + quad * 8);
        if (ck < 224) {
            #pragma unroll
            for (int ot = 0; ot < 10; ++ot)
                awn[ot] = *(const bf16x8*)(wp + (size_t)ot * 16 * 256 + ck + 32);
        }
        #pragma unroll
        for (int ot = 0; ot < 10; ++ot)
            acc[ot] = __builtin_amdgcn_mfma_f32_16x16x32_bf16(awc[ot], bx, acc[ot], 0, 0, 0);
        #pragma unroll
        for (int ot = 0; ot < 10; ++ot) awc[ot] = awn[ot];
    }
    __syncthreads();   // xT dead; reuse smem

    // ---- bias + stage
    #pragma unroll
    for (int ot = 0; ot < 10; ++ot) {
        #pragma unroll
        for (int r = 0; r < 4; ++r) {
            int o = obase + 16 * ot + 4 * quad + r;
            float bias = (o < 32) ? key_b[o] : (o < 64) ? query_b[o - 32] : value_b[o - 64];
            unsigned short val = f2bf(acc[ot][r] + bias);
            if (o < 64) KQS(ns + mrow, o) = val;
            else        VS(ns >> 4, o - 64, mrow) = val;
        }
    }
    __syncthreads();

    // ---- coalesced stores: k/q
    {
        int n = t >> 3, o4 = (t & 7) * 4;
        *(us4*)&kT[((size_t)b * NPIX + n0 + n) * CK_DIM + o4] = *(const us4*)&KQS(n, o4);
        *(us4*)&qT[((size_t)b * NPIX + n0 + n) * CK_DIM + o4] = *(const us4*)&KQS(n, 32 + o4);
    }
    // ---- coalesced stores: v
    #pragma unroll
    for (int it = 0; it < 8; ++it) {
        int flat = it * 256 + t;
        int nsb = flat >> 10, c = (flat >> 2) & 255, nn = (flat & 3) * 4;
        unsigned short* vbase = vt + ((size_t)b * (NPIX / 16) + n0 / 16 + nsb) * (C_DIM * 16);
        *(us4*)&vbase[c * 16 + nn] = *(const us4*)&VS(nsb, c, nn);
    }
    #undef XT
    #undef VS
    #undef KQS
}

// ---------------------------------------------------------------------------
// Kernel B: BARRIER-FREE fused attention. Block = (i-tile 32, b), 512 blocks.
// Wave w = (j-strip jh = w&1, c-half ch = w>>1). Each wave computes S/exp for
// its OWN 32-j strip (P kept in a wave-private LDS region -> no cross-wave
// handoff, ZERO barriers in the j-loop), then PV for its 128-c strip using
// only its j-strip. S/exp duplicated across the two ch waves (cheap VALU,
// now fully overlapped with MFMA). One barrier total (l reduction).
// ---------------------------------------------------------------------------
__global__ __launch_bounds__(256) void attn_kernel(
    const unsigned short* __restrict__ kT,
    const unsigned short* __restrict__ qT,
    const unsigned short* __restrict__ vt,
    const float* __restrict__ x, const float* __restrict__ alpha,
    float* __restrict__ out)
{
    const int f  = blockIdx.x;                   // 0..511
    const int b  = (f & 7) >> 1;                 // XCD-pair -> batch (vt L2-local)
    const int i0 = ((f >> 3) * 2 + (f & 1)) * 32;
    const int t  = threadIdx.x;
    const int w    = t >> 6;
    const int lane = t & 63;
    const int mrow = lane & 15;
    const int quad = lane >> 4;
    const int m32  = lane & 31;
    const int half = lane >> 5;
    const int jh   = w & 1;          // j-strip half within 64-j supertile
    const int c0   = (w >> 1) * 128; // c-half

    // wave-private P regions: [wave][pp][i 32][j 32+8pad] -> no j-loop barriers
    __shared__ __align__(16) unsigned short P[4][2][32][40];
    __shared__ float lred[4][32];

    const unsigned short* kTb = kT + (size_t)b * NPIX * CK_DIM;
    const unsigned short* qTb = qT + (size_t)b * NPIX * CK_DIM;
    const unsigned short* vtb = vt + (size_t)b * (NPIX / 16) * (C_DIM * 16);

    bf16x8 kf[2];
    #pragma unroll
    for (int is = 0; is < 2; ++is)
        kf[is] = *(const bf16x8*)(kTb + (size_t)(i0 + 16 * is + mrow) * CK_DIM + quad * 8);

    f32x16 acc[4];   // c-tiles c0+32ct, i-tile 32
    #pragma unroll
    for (int ct = 0; ct < 4; ++ct)
        #pragma unroll
        for (int r = 0; r < 16; ++r) acc[ct][r] = 0.0f;

    float lacc[2] = {0.0f, 0.0f};
    int pp = 0;

    for (int jt = 0; jt < NPIX; jt += 64) {
        const int jw = jt + 32 * jh;     // this wave's 32-j strip

        // prefetch V A-frags: [c-tile ct][j-sub kh], 1KB-contiguous per load
        bf16x8 av[4][2];
        #pragma unroll
        for (int ct = 0; ct < 4; ++ct)
            #pragma unroll
            for (int kh = 0; kh < 2; ++kh)
                av[ct][kh] = *(const bf16x8*)(vtb
                    + (size_t)(jw / 16 + kh) * (C_DIM * 16)
                    + (size_t)(c0 + 32 * ct + m32) * 16 + half * 8);

        // S^T for own strip -> exp -> wave-private P[i][j]
        #pragma unroll
        for (int js = 0; js < 2; ++js) {
            bf16x8 aq = *(const bf16x8*)(qTb + (size_t)(jw + 16 * js + mrow) * CK_DIM + quad * 8);
            #pragma unroll
            for (int is = 0; is < 2; ++is) {
                f32x4 d = __builtin_amdgcn_mfma_f32_16x16x32_bf16(
                    aq, kf[is], (f32x4){0.f, 0.f, 0.f, 0.f}, 0, 0, 0);
                float p0 = __expf(d[0]), p1 = __expf(d[1]);
                float p2 = __expf(d[2]), p3 = __expf(d[3]);
                lacc[is] += (p0 + p1) + (p2 + p3);
                us4 p;
                p.x = f2bf(p0); p.y = f2bf(p1); p.z = f2bf(p2); p.w = f2bf(p3);
                // P[i = 16is+mrow][j = 16js+4quad .. +3]
                *(us4*)&P[w][pp][16 * is + mrow][16 * js + 4 * quad] = p;
            }
        }

        // PV: acc[ct] += V[c][j-strip] . P^T ; B-frag = P rows (own region,
        // same-wave in-order LDS -> compiler's lgkmcnt suffices, no barrier)
        #pragma unroll
        for (int kh = 0; kh < 2; ++kh) {
            bf16x8 bp = *(const bf16x8*)&P[w][pp][m32][16 * kh + half * 8];
            #pragma unroll
            for (int ct = 0; ct < 4; ++ct)
                acc[ct] = __builtin_amdgcn_mfma_f32_32x32x16_bf16(av[ct][kh], bp, acc[ct], 0, 0, 0);
        }
        pp ^= 1;
    }

    // l_i: quad-reduce (j within strip), then cross-wave; ch-pair duplicates -> x0.5
    #pragma unroll
    for (int is = 0; is < 2; ++is) {
        lacc[is] += __shfl_xor(lacc[is], 16);
        lacc[is] += __shfl_xor(lacc[is], 32);
    }
    if (lane < 16) {
        #pragma unroll
        for (int is = 0; is < 2; ++is) lred[w][16 * is + lane] = lacc[is];
    }
    __syncthreads();

    const float al = alpha[0];
    float l = ((lred[0][m32] + lred[1][m32]) + (lred[2][m32] + lred[3][m32])) * 0.5f;
    float rs = al / l;

    const float* xb = x + (size_t)b * C_DIM * NPIX;
    float* ob = out + (size_t)b * C_DIM * NPIX;
    const int i = i0 + m32;
    #pragma unroll
    for (int ct = 0; ct < 4; ++ct)
        #pragma unroll
        for (int r = 0; r < 16; ++r) {
            int c = c0 + 32 * ct + (r & 3) + 8 * (r >> 2) + 4 * half;
            size_t idx = (size_t)c * NPIX + i;
            ob[idx] = acc[ct][r] * rs + xb[idx];
        }
}

// ---------------------------------------------------------------------------
extern "C" void kernel_launch(void* const* d_in, const int* in_sizes, int n_in,
                              void* d_out, int out_size, void* d_ws, size_t ws_size,
                              hipStream_t stream) {
    const float* x       = (const float*)d_in[0];
    const float* key_W   = (const float*)d_in[1];
    const float* key_b   = (const float*)d_in[2];
    const float* query_W = (const float*)d_in[3];
    const float* query_b = (const float*)d_in[4];
    const float* value_W = (const float*)d_in[5];
    const float* value_b = (const float*)d_in[6];
    const float* alpha   = (const float*)d_in[7];
    float* out = (float*)d_out;

    unsigned short* kT  = (unsigned short*)d_ws;                 // [B][N][32]       1 MB
    unsigned short* qT  = kT + (size_t)BATCH * NPIX * CK_DIM;    // [B][N][32]       1 MB
    unsigned short* vt  = qT + (size_t)BATCH * NPIX * CK_DIM;    // [B][N/16][C][16] 8 MB
    unsigned short* wbf = vt + (size_t)BATCH * C_DIM * NPIX;     // [320][256]       160 KB

    wprep_kernel<<<80, 256, 0, stream>>>(key_W, query_W, value_W, wbf);

    dim3 gridA(NPIX / 32, BATCH);
    proj_kernel<<<gridA, 256, 0, stream>>>(x, wbf, key_b, query_b, value_b, kT, qT, vt);

    attn_kernel<<<512, 256, 0, stream>>>(kT, qT, vt, x, alpha, out);
}

// Round 8
// 150.606 us; speedup vs baseline: 1.3125x; 1.3125x over previous
//
#include <hip/hip_runtime.h>

#define C_DIM 256
#define CK_DIM 32
#define NPIX 4096
#define BATCH 4

typedef __attribute__((ext_vector_type(8))) short bf16x8;     // 8 bf16 = 4 VGPRs
typedef __attribute__((ext_vector_type(4))) float f32x4;
typedef __attribute__((ext_vector_type(16))) float f32x16;
typedef __attribute__((ext_vector_type(4))) unsigned short us4;

__device__ __forceinline__ unsigned short f2bf(float f) {
    union { float f; unsigned int u; } c; c.f = f;
    unsigned int r = c.u + 0x7FFFu + ((c.u >> 16) & 1u);
    return (unsigned short)(r >> 16);
}

// ---------------------------------------------------------------------------
// Kernel 0: pack W (key 0..31, query 32..63, value 64..319) into bf16 [320][256]
// ---------------------------------------------------------------------------
__global__ __launch_bounds__(256) void wprep_kernel(
    const float* __restrict__ kW, const float* __restrict__ qW,
    const float* __restrict__ vW, unsigned short* __restrict__ wbf)
{
    int i4 = (blockIdx.x * 256 + threadIdx.x) * 4;
    int o = i4 >> 8, c = i4 & 255;
    const float* src = (o < 32) ? kW + o * 256 + c
                     : (o < 64) ? qW + (o - 32) * 256 + c
                                : vW + (o - 64) * 256 + c;
    float4 f = *(const float4*)src;
    us4 p; p.x = f2bf(f.x); p.y = f2bf(f.y); p.z = f2bf(f.z); p.w = f2bf(f.w);
    *(us4*)&wbf[i4] = p;
}

// ---------------------------------------------------------------------------
// Kernel A: MFMA projections (unchanged from R7; true cost measured next round)
// ---------------------------------------------------------------------------
#define XP 264
__global__ __launch_bounds__(256) void proj_kernel(
    const float* __restrict__ x,
    const unsigned short* __restrict__ wbf,
    const float* __restrict__ key_b, const float* __restrict__ query_b,
    const float* __restrict__ value_b,
    unsigned short* __restrict__ kT,
    unsigned short* __restrict__ qT,
    unsigned short* __restrict__ vt)
{
    const int b  = blockIdx.y;
    const int n0 = blockIdx.x * 32;
    const int t  = threadIdx.x;
    const int w    = t >> 6;
    const int lane = t & 63;
    const int mrow = lane & 15;
    const int quad = lane >> 4;
    const int oh   = w >> 1;
    const int ns   = (w & 1) * 16;

    __shared__ __align__(16) unsigned short smem[14592];
    #define XT(n, c)       smem[(n) * XP + (c)]
    #define VS(nsb, c, nn) smem[(nsb) * 6144 + (c) * 24 + (nn)]
    #define KQS(n, o)      smem[12288 + (n) * 72 + (o)]

    const float* xb = x + (size_t)b * C_DIM * NPIX + n0;
    const int cb = (t >> 3) * 4;
    const int n4 = (t & 7) * 4;
    #pragma unroll
    for (int it = 0; it < 2; ++it) {
        int c0 = it * 128 + cb;
        float4 r0 = *(const float4*)(xb + (size_t)(c0 + 0) * NPIX + n4);
        float4 r1 = *(const float4*)(xb + (size_t)(c0 + 1) * NPIX + n4);
        float4 r2 = *(const float4*)(xb + (size_t)(c0 + 2) * NPIX + n4);
        float4 r3 = *(const float4*)(xb + (size_t)(c0 + 3) * NPIX + n4);
        float d0[4] = {r0.x, r0.y, r0.z, r0.w};
        float d1[4] = {r1.x, r1.y, r1.z, r1.w};
        float d2[4] = {r2.x, r2.y, r2.z, r2.w};
        float d3[4] = {r3.x, r3.y, r3.z, r3.w};
        #pragma unroll
        for (int d = 0; d < 4; ++d) {
            us4 p; p.x = f2bf(d0[d]); p.y = f2bf(d1[d]);
                   p.z = f2bf(d2[d]); p.w = f2bf(d3[d]);
            *(us4*)&XT(n4 + d, c0) = p;
        }
    }
    __syncthreads();

    f32x4 acc[10];
    #pragma unroll
    for (int ot = 0; ot < 10; ++ot) acc[ot] = (f32x4){0.f, 0.f, 0.f, 0.f};
    const int obase = oh * 160;
    const unsigned short* wp = wbf + (size_t)(obase + mrow) * 256 + quad * 8;

    bf16x8 awc[10], awn[10];
    #pragma unroll
    for (int ot = 0; ot < 10; ++ot)
        awc[ot] = *(const bf16x8*)(wp + (size_t)ot * 16 * 256);

    #pragma unroll
    for (int ck = 0; ck < 256; ck += 32) {
        bf16x8 bx = *(const bf16x8*)&XT(ns + mrow, ck + quad * 8);
        if (ck < 224) {
            #pragma unroll
            for (int ot = 0; ot < 10; ++ot)
                awn[ot] = *(const bf16x8*)(wp + (size_t)ot * 16 * 256 + ck + 32);
        }
        #pragma unroll
        for (int ot = 0; ot < 10; ++ot)
            acc[ot] = __builtin_amdgcn_mfma_f32_16x16x32_bf16(awc[ot], bx, acc[ot], 0, 0, 0);
        #pragma unroll
        for (int ot = 0; ot < 10; ++ot) awc[ot] = awn[ot];
    }
    __syncthreads();

    #pragma unroll
    for (int ot = 0; ot < 10; ++ot) {
        #pragma unroll
        for (int r = 0; r < 4; ++r) {
            int o = obase + 16 * ot + 4 * quad + r;
            float bias = (o < 32) ? key_b[o] : (o < 64) ? query_b[o - 32] : value_b[o - 64];
            unsigned short val = f2bf(acc[ot][r] + bias);
            if (o < 64) KQS(ns + mrow, o) = val;
            else        VS(ns >> 4, o - 64, mrow) = val;
        }
    }
    __syncthreads();

    {
        int n = t >> 3, o4 = (t & 7) * 4;
        *(us4*)&kT[((size_t)b * NPIX + n0 + n) * CK_DIM + o4] = *(const us4*)&KQS(n, o4);
        *(us4*)&qT[((size_t)b * NPIX + n0 + n) * CK_DIM + o4] = *(const us4*)&KQS(n, 32 + o4);
    }
    #pragma unroll
    for (int it = 0; it < 8; ++it) {
        int flat = it * 256 + t;
        int nsb = flat >> 10, c = (flat >> 2) & 255, nn = (flat & 3) * 4;
        unsigned short* vbase = vt + ((size_t)b * (NPIX / 16) + n0 / 16 + nsb) * (C_DIM * 16);
        *(us4*)&vbase[c * 16 + nn] = *(const us4*)&VS(nsb, c, nn);
    }
    #undef XT
    #undef VS
    #undef KQS
}

// ---------------------------------------------------------------------------
// Kernel B: producer/consumer fused attention. Block = 512 threads (8 waves),
// grid 256 = (i-tile 64) x B, XCD-swizzled. Waves 0-3 PRODUCE: S^T MFMA + exp
// -> Pt[pp^1] for tile jt+128 (aq prefetched a tile ahead). Waves 4-7 CONSUME:
// PV 32x32x16 MFMA on Pt[pp] (av prefetched pre-barrier so the vmcnt drain
// overlaps the barrier wait). VALU (producers) and MFMA (consumers) co-
// schedule on the same SIMDs (m114). One barrier per j-tile.
// ---------------------------------------------------------------------------
__global__ __launch_bounds__(512) void attn_kernel(
    const unsigned short* __restrict__ kT,
    const unsigned short* __restrict__ qT,
    const unsigned short* __restrict__ vt,
    const float* __restrict__ x, const float* __restrict__ alpha,
    float* __restrict__ out)
{
    const int f  = blockIdx.x;                   // 0..255
    const int b  = (f & 7) >> 1;                 // XCD-pair -> batch (vt L2-local)
    const int i0 = ((f >> 3) * 2 + (f & 1)) * 64;
    const int t  = threadIdx.x;
    const int w    = t >> 6;                     // 0..7
    const int lane = t & 63;
    const int mrow = lane & 15;
    const int quad = lane >> 4;
    const int m32  = lane & 31;
    const int half = lane >> 5;

    __shared__ __align__(16) unsigned short Pt[2][64][136];  // ping-pong, 34.8KB
    __shared__ float lred[4][64];

    const unsigned short* kTb = kT + (size_t)b * NPIX * CK_DIM;
    const unsigned short* qTb = qT + (size_t)b * NPIX * CK_DIM;
    const unsigned short* vtb = vt + (size_t)b * (NPIX / 16) * (C_DIM * 16);

    int pp = 0;

    if (w < 4) {
        // ================= PRODUCER =================
        const int pw = w;
        bf16x8 kf[4];
        #pragma unroll
        for (int is = 0; is < 4; ++is)
            kf[is] = *(const bf16x8*)(kTb + (size_t)(i0 + 16 * is + mrow) * CK_DIM + quad * 8);

        float lacc[4] = {0.f, 0.f, 0.f, 0.f};

        // produce tile 0 into Pt[0]
        #pragma unroll
        for (int js = 0; js < 2; ++js) {
            bf16x8 aq = *(const bf16x8*)(qTb + (size_t)(32 * pw + 16 * js + mrow) * CK_DIM + quad * 8);
            #pragma unroll
            for (int is = 0; is < 4; ++is) {
                f32x4 d = __builtin_amdgcn_mfma_f32_16x16x32_bf16(
                    aq, kf[is], (f32x4){0.f, 0.f, 0.f, 0.f}, 0, 0, 0);
                float p0 = __expf(d[0]), p1 = __expf(d[1]);
                float p2 = __expf(d[2]), p3 = __expf(d[3]);
                lacc[is] += (p0 + p1) + (p2 + p3);
                us4 p; p.x = f2bf(p0); p.y = f2bf(p1); p.z = f2bf(p2); p.w = f2bf(p3);
                *(us4*)&Pt[0][16 * is + mrow][32 * pw + 16 * js + 4 * quad] = p;
            }
        }
        // prefetch aq for tile 128
        bf16x8 aqc[2];
        #pragma unroll
        for (int js = 0; js < 2; ++js)
            aqc[js] = *(const bf16x8*)(qTb + (size_t)(128 + 32 * pw + 16 * js + mrow) * CK_DIM + quad * 8);

        __syncthreads();

        for (int jt = 0; jt < NPIX; jt += 128) {
            // prefetch aq for tile jt+256 (wrapped; wasted only on last iters)
            bf16x8 aqn[2];
            int jpre = (jt + 256) & (NPIX - 1);
            #pragma unroll
            for (int js = 0; js < 2; ++js)
                aqn[js] = *(const bf16x8*)(qTb + (size_t)(jpre + 32 * pw + 16 * js + mrow) * CK_DIM + quad * 8);

            if (jt + 128 < NPIX) {
                // produce tile jt+128 into Pt[pp^1]
                #pragma unroll
                for (int js = 0; js < 2; ++js) {
                    #pragma unroll
                    for (int is = 0; is < 4; ++is) {
                        f32x4 d = __builtin_amdgcn_mfma_f32_16x16x32_bf16(
                            aqc[js], kf[is], (f32x4){0.f, 0.f, 0.f, 0.f}, 0, 0, 0);
                        float p0 = __expf(d[0]), p1 = __expf(d[1]);
                        float p2 = __expf(d[2]), p3 = __expf(d[3]);
                        lacc[is] += (p0 + p1) + (p2 + p3);
                        us4 p; p.x = f2bf(p0); p.y = f2bf(p1); p.z = f2bf(p2); p.w = f2bf(p3);
                        *(us4*)&Pt[pp ^ 1][16 * is + mrow][32 * pw + 16 * js + 4 * quad] = p;
                    }
                }
            }
            aqc[0] = aqn[0]; aqc[1] = aqn[1];
            __syncthreads();
            pp ^= 1;
        }

        // l reduction: quads -> lanes 0..15, write partials
        #pragma unroll
        for (int is = 0; is < 4; ++is) {
            lacc[is] += __shfl_xor(lacc[is], 16);
            lacc[is] += __shfl_xor(lacc[is], 32);
        }
        if (lane < 16) {
            #pragma unroll
            for (int is = 0; is < 4; ++is) lred[pw][16 * is + lane] = lacc[is];
        }
        __syncthreads();
    } else {
        // ================= CONSUMER =================
        const int cw = w - 4;
        const int c0 = cw * 64;

        f32x16 acc[2][2];   // [c-half 32][i-half 32]
        #pragma unroll
        for (int cs = 0; cs < 2; ++cs)
            #pragma unroll
            for (int ih = 0; ih < 2; ++ih)
                #pragma unroll
                for (int r = 0; r < 16; ++r) acc[cs][ih][r] = 0.0f;

        // preload av for tile 0
        bf16x8 av[8][2];
        #pragma unroll
        for (int jb = 0; jb < 8; ++jb) {
            const unsigned short* vp = vtb + (size_t)jb * (C_DIM * 16)
                                       + (size_t)(c0 + m32) * 16 + half * 8;
            av[jb][0] = *(const bf16x8*)vp;
            av[jb][1] = *(const bf16x8*)(vp + 32 * 16);
        }
        __syncthreads();

        for (int jt = 0; jt < NPIX; jt += 128) {
            // PV on Pt[pp] (tile jt)
            #pragma unroll
            for (int jb = 0; jb < 8; ++jb) {
                bf16x8 bp0 = *(const bf16x8*)&Pt[pp][m32][16 * jb + half * 8];
                bf16x8 bp1 = *(const bf16x8*)&Pt[pp][32 + m32][16 * jb + half * 8];
                acc[0][0] = __builtin_amdgcn_mfma_f32_32x32x16_bf16(av[jb][0], bp0, acc[0][0], 0, 0, 0);
                acc[1][0] = __builtin_amdgcn_mfma_f32_32x32x16_bf16(av[jb][1], bp0, acc[1][0], 0, 0, 0);
                acc[0][1] = __builtin_amdgcn_mfma_f32_32x32x16_bf16(av[jb][0], bp1, acc[0][1], 0, 0, 0);
                acc[1][1] = __builtin_amdgcn_mfma_f32_32x32x16_bf16(av[jb][1], bp1, acc[1][1], 0, 0, 0);
            }
            // prefetch av for tile jt+128 (wrapped; drains during the barrier)
            int jpre = (jt + 128) & (NPIX - 1);
            #pragma unroll
            for (int jb = 0; jb < 8; ++jb) {
                const unsigned short* vp = vtb + (size_t)(jpre / 16 + jb) * (C_DIM * 16)
                                           + (size_t)(c0 + m32) * 16 + half * 8;
                av[jb][0] = *(const bf16x8*)vp;
                av[jb][1] = *(const bf16x8*)(vp + 32 * 16);
            }
            __syncthreads();
            pp ^= 1;
        }
        __syncthreads();   // producers' lred now visible

        const float al = alpha[0];
        float rs[2];
        #pragma unroll
        for (int ih = 0; ih < 2; ++ih) {
            int li = 32 * ih + m32;
            float l = (lred[0][li] + lred[1][li]) + (lred[2][li] + lred[3][li]);
            rs[ih] = al / l;
        }

        const float* xb = x + (size_t)b * C_DIM * NPIX;
        float* ob = out + (size_t)b * C_DIM * NPIX;
        #pragma unroll
        for (int cs = 0; cs < 2; ++cs)
            #pragma unroll
            for (int ih = 0; ih < 2; ++ih) {
                int i = i0 + 32 * ih + m32;
                #pragma unroll
                for (int r = 0; r < 16; ++r) {
                    int c = c0 + 32 * cs + (r & 3) + 8 * (r >> 2) + 4 * half;
                    size_t idx = (size_t)c * NPIX + i;
                    ob[idx] = acc[cs][ih][r] * rs[ih] + xb[idx];
                }
            }
    }
}

// ---------------------------------------------------------------------------
extern "C" void kernel_launch(void* const* d_in, const int* in_sizes, int n_in,
                              void* d_out, int out_size, void* d_ws, size_t ws_size,
                              hipStream_t stream) {
    const float* x       = (const float*)d_in[0];
    const float* key_W   = (const float*)d_in[1];
    const float* key_b   = (const float*)d_in[2];
    const float* query_W = (const float*)d_in[3];
    const float* query_b = (const float*)d_in[4];
    const float* value_W = (const float*)d_in[5];
    const float* value_b = (const float*)d_in[6];
    const float* alpha   = (const float*)d_in[7];
    float* out = (float*)d_out;

    unsigned short* kT  = (unsigned short*)d_ws;                 // [B][N][32]       1 MB
    unsigned short* qT  = kT + (size_t)BATCH * NPIX * CK_DIM;    // [B][N][32]       1 MB
    unsigned short* vt  = qT + (size_t)BATCH * NPIX * CK_DIM;    // [B][N/16][C][16] 8 MB
    unsigned short* wbf = vt + (size_t)BATCH * C_DIM * NPIX;     // [320][256]       160 KB

    wprep_kernel<<<80, 256, 0, stream>>>(key_W, query_W, value_W, wbf);

    dim3 gridA(NPIX / 32, BATCH);
    proj_kernel<<<gridA, 256, 0, stream>>>(x, wbf, key_b, query_b, value_b, kT, qT, vt);

    attn_kernel<<<256, 512, 0, stream>>>(kT, qT, vt, x, alpha, out);
}